// Round 5
// baseline (320.618 us; speedup 1.0000x reference)
//
#include <hip/hip_runtime.h>
#include <hip/hip_cooperative_groups.h>

namespace cg = cooperative_groups;

// AccSeeds, single cooperative kernel.
// Phases: A hist(32 blk) |g| B merge(32 blk) |g| C scan/cutoff(blk 0) |g|
//         D gather(all)  |g| E rank(all, 2x4x32) -> group tickets(8) ->
//         group winners bucket -> final ticket -> winner scans + writes.
// 13-bit bins: cutoff bin ~700 elems; candidates ~2700 < CAP 4096.

#define HW_N   262144
#define NB     8192
#define HBLK   32
#define CAP    4096
#define K_SEL  2000
#define N_THR  200
#define NBLK   256
#define JCH    32     // j-chunks per side
#define CCH    4      // cand-chunks of 1024
#define NGRP   8      // 2 sides * CCH

__device__ unsigned g_bhist[HBLK * NB];
__device__ unsigned g_hist[NB];
__device__ unsigned g_hdr[4] = {0, 0, 0, 0};  // 0:T_bot 1:T_top 2:cnt_bot 3:cnt_top
__device__ unsigned g_gt[NGRP] = {0};         // group tickets (self-resetting)
__device__ unsigned g_ft = 0;                 // final ticket (self-resetting)
__device__ unsigned long long g_top[CAP];     // (~key<<32)|idx : asc = desc value
__device__ unsigned long long g_bot[CAP];     // ( key<<32)|idx : asc = asc value
__device__ unsigned g_prank[2][CAP][JCH];
__device__ float g_pbuck[NGRP][256];

__device__ __forceinline__ unsigned key_of(float x) {
    unsigned u = __float_as_uint(x);
    return (u & 0x80000000u) ? ~u : (u | 0x80000000u);  // ascending key == ascending float
}

__global__ __launch_bounds__(1024) void k_all(const float* __restrict__ cam,
                                              const float* __restrict__ mask,
                                              float* __restrict__ out) {
    cg::grid_group grid = cg::this_grid();
    __shared__ unsigned long long shmem8[NB / 2];   // 32 KB, multi-purpose
    unsigned* sh = (unsigned*)shmem8;
    const unsigned tid = threadIdx.x;
    const unsigned b = blockIdx.x;

    // ---- Phase A: blocks 0..31 histogram 8192 elems each (LDS-private) ----
    if (b < HBLK) {
        #pragma unroll
        for (int i = 0; i < NB / 1024; i++) sh[tid + i * 1024] = 0;
        __syncthreads();
        const float4* cam4 = (const float4*)cam;
        #pragma unroll
        for (int r = 0; r < 2; r++) {
            float4 v = cam4[b * 2048 + r * 1024 + tid];
            atomicAdd(&sh[key_of(v.x) >> 19], 1u);
            atomicAdd(&sh[key_of(v.y) >> 19], 1u);
            atomicAdd(&sh[key_of(v.z) >> 19], 1u);
            atomicAdd(&sh[key_of(v.w) >> 19], 1u);
        }
        __syncthreads();
        #pragma unroll
        for (int i = 0; i < NB / 1024; i++)
            g_bhist[b * NB + tid + i * 1024] = sh[tid + i * 1024];
        __threadfence();
    }
    grid.sync();

    // ---- Phase B: blocks 0..31 merge one 256-bin slab each ----
    if (b < HBLK) {
        if (tid < 256) {
            const unsigned bin = b * 256 + tid;
            unsigned s = 0;
            #pragma unroll 8
            for (int sd = 0; sd < HBLK; sd++) s += g_bhist[sd * NB + bin];
            g_hist[bin] = s;
        }
        if (b == 0 && tid == 0) { g_hdr[2] = 0; g_hdr[3] = 0; }
        __threadfence();
    }
    grid.sync();

    // ---- Phase C: block 0 scans 8192 bins -> cutoff bins ----
    if (b == 0) {
        unsigned c[8];
        const uint4* gh = (const uint4*)g_hist;
        uint4 lo4 = gh[2 * tid], hi4 = gh[2 * tid + 1];
        c[0] = lo4.x; c[1] = lo4.y; c[2] = lo4.z; c[3] = lo4.w;
        c[4] = hi4.x; c[5] = hi4.y; c[6] = hi4.z; c[7] = hi4.w;
        unsigned chunk = 0;
        #pragma unroll
        for (int i = 0; i < 8; i++) chunk += c[i];
        sh[tid] = chunk;
        __syncthreads();
        for (unsigned off = 1; off < 1024; off <<= 1) {   // Hillis-Steele inclusive
            unsigned v = (tid >= off) ? sh[tid - off] : 0u;
            __syncthreads();
            if (tid >= off) sh[tid] += v;
            __syncthreads();
        }
        const unsigned r_bot = K_SEL - 1, r_top = HW_N - K_SEL;
        unsigned run = sh[tid] - chunk;
        #pragma unroll
        for (int i = 0; i < 8; i++) {
            unsigned nxt = run + c[i];
            if (run <= r_bot && nxt > r_bot) g_hdr[0] = 8 * tid + i;
            if (run <= r_top && nxt > r_top) g_hdr[1] = 8 * tid + i;
            run = nxt;
        }
        __threadfence();
    }
    grid.sync();

    // ---- Phase D: all 256 blocks gather (ballot-aggregated append) ----
    {
        __shared__ unsigned s_ot[16], s_ob[16], s_bt, s_bb;
        const unsigned i = b * 1024 + tid;
        const unsigned Tb = g_hdr[0], Tt = g_hdr[1];
        const unsigned k = key_of(cam[i]);
        const unsigned bin = k >> 19;
        const bool ft = (bin >= Tt), fb2 = (bin <= Tb);
        const unsigned long long mt = __ballot(ft), mb = __ballot(fb2);
        const unsigned lane = tid & 63, w = tid >> 6;
        if (lane == 0) { s_ot[w] = (unsigned)__popcll(mt); s_ob[w] = (unsigned)__popcll(mb); }
        __syncthreads();
        if (tid == 0) {
            unsigned at = 0, ab = 0;
            #pragma unroll
            for (int j = 0; j < 16; j++) {
                unsigned v = s_ot[j]; s_ot[j] = at; at += v;
                v = s_ob[j]; s_ob[j] = ab; ab += v;
            }
            s_bt = at ? atomicAdd(&g_hdr[3], at) : 0u;
            s_bb = ab ? atomicAdd(&g_hdr[2], ab) : 0u;
        }
        __syncthreads();
        const unsigned long long lmask = (1ull << lane) - 1ull;
        if (ft) {
            unsigned pos = s_bt + s_ot[w] + (unsigned)__popcll(mt & lmask);
            if (pos < CAP) g_top[pos] = ((unsigned long long)(~k) << 32) | i;
        }
        if (fb2) {
            unsigned pos = s_bb + s_ob[w] + (unsigned)__popcll(mb & lmask);
            if (pos < CAP) g_bot[pos] = ((unsigned long long)k << 32) | i;
        }
        __threadfence();
    }
    grid.sync();

    // ---- Phase E: all-pairs rank, 2 sides x 4 cand-chunks x 32 j-chunks ----
    const unsigned side = b & 1;           // 0: top/forg, 1: bot/backg
    const unsigned q = b >> 1;
    const unsigned cc = q >> 5;            // 0..3
    const unsigned jc = q & 31;            // 0..31
    unsigned cnt = (side == 0) ? g_hdr[3] : g_hdr[2];
    if (cnt > CAP) cnt = CAP;
    const unsigned long long* rec = (side == 0) ? g_top : g_bot;
    const unsigned lo = (jc * cnt) >> 5, hi = ((jc + 1) * cnt) >> 5;
    const unsigned len = hi - lo;
    unsigned long long* sj = shmem8;       // reuse LDS: <=128 u64
    for (unsigned e = tid; e < len; e += 1024) sj[e] = rec[lo + e];
    __syncthreads();
    const unsigned c = cc * 1024 + tid;
    if (c < cnt) {
        const unsigned long long my = rec[c];
        unsigned r0 = 0, r1 = 0, r2 = 0, r3 = 0;
        unsigned j = 0;
        for (; j + 8 <= len; j += 8) {     // ILP: 4 accumulators, batched LDS reads
            r0 += (sj[j + 0] < my); r1 += (sj[j + 1] < my);
            r2 += (sj[j + 2] < my); r3 += (sj[j + 3] < my);
            r0 += (sj[j + 4] < my); r1 += (sj[j + 5] < my);
            r2 += (sj[j + 6] < my); r3 += (sj[j + 7] < my);
        }
        for (; j < len; j++) r0 += (sj[j] < my);
        g_prank[side][c][jc] = r0 + r1 + r2 + r3;   // exact stable partial rank
    }
    __syncthreads();

    // group ticket: last of 32 j-blocks per (side, cand-chunk) reduces
    __shared__ bool s_lastg;
    const unsigned grp = side * CCH + cc;
    if (tid == 0) {
        __threadfence();                   // release partial ranks
        unsigned t = atomicAdd(&g_gt[grp], 1u);
        s_lastg = (t == JCH - 1);
        if (s_lastg) g_gt[grp] = 0;
    }
    __syncthreads();
    if (!s_lastg) return;                  // no grid syncs remain — safe to exit
    __threadfence();                       // acquire group partials

    float* bucket = (float*)shmem8;
    if (tid < 256) bucket[tid] = 0.0f;
    __syncthreads();
    if (c < cnt) {
        const uint4* p = (const uint4*)&g_prank[side][c][0];
        unsigned r = 0;
        #pragma unroll
        for (int i = 0; i < 8; i++) {
            uint4 a = p[i];
            r += a.x + a.y + a.z + a.w;
        }
        if (r < K_SEL) {
            unsigned idx = (unsigned)rec[c];
            float m = mask[idx];
            atomicAdd(&bucket[r / 10], (side == 0) ? m : 1.0f - m);
        }
    }
    __syncthreads();
    if (tid < 256) g_pbuck[grp][tid] = bucket[tid];
    __syncthreads();

    // final ticket: last of 8 group winners sums, scans, writes 400 outputs
    __shared__ bool s_lastf;
    if (tid == 0) {
        __threadfence();                   // release group buckets
        unsigned t = atomicAdd(&g_ft, 1u);
        s_lastf = (t == NGRP - 1);
        if (s_lastf) g_ft = 0;
    }
    __syncthreads();
    if (!s_lastf) return;
    __threadfence();                       // acquire all group buckets

    float* fbk = (float*)shmem8;           // [2][256]
    if (tid < 512) {
        const unsigned s = tid >> 8, bin = tid & 255;
        float v = 0.0f;
        #pragma unroll
        for (int g = 0; g < CCH; g++) v += g_pbuck[s * CCH + g][bin];
        fbk[tid] = v;
    }
    __syncthreads();
    for (unsigned off = 1; off < 256; off <<= 1) {   // scan both sides at once
        float v = 0.0f;
        if (tid < 512 && (tid & 255) >= off) v = fbk[tid - off];
        __syncthreads();
        if (tid < 512 && (tid & 255) >= off) fbk[tid] += v;
        __syncthreads();
    }
    if (tid < N_THR) {
        out[tid]         = 100.0f * fbk[tid] / (float)(10 * (tid + 1));
        out[N_THR + tid] = 100.0f * fbk[256 + tid] / (float)(10 * (tid + 1));
    }
}

extern "C" void kernel_launch(void* const* d_in, const int* in_sizes, int n_in,
                              void* d_out, int out_size, void* d_ws, size_t ws_size,
                              hipStream_t stream) {
    const float* cam  = (const float*)d_in[0];
    const float* mask = (const float*)d_in[1];
    float* out = (float*)d_out;
    void* args[] = { (void*)&cam, (void*)&mask, (void*)&out };
    hipLaunchCooperativeKernel((const void*)k_all, dim3(NBLK), dim3(1024), args, 0, stream);
}

// Round 6
// 103.450 us; speedup vs baseline: 3.0992x; 3.0992x over previous
//
#include <hip/hip_runtime.h>

// AccSeeds: exact top-K/bottom-K selection + per-threshold prefix accuracy.
// cam: (512*512) f32, true_mask: (512*512) f32 (0/1).
// out: acc_forg[200] ++ acc_backg[200] (float32), z = 10,20,...,2000.
//
// 3 dispatches (cooperative grid.sync measured ~55-60us/sync on MI355X in R5
// — kernel boundaries are cheaper):
//  D1 k_hist_cut : 8 blocks  — per-block LDS hist (13-bit bins); ticket winner
//                  merges 8 hists + scans 8192 bins -> cutoff bins.
//  D2 k_gather   : 256 blocks — ballot-aggregated candidate append.
//  D3 k_rank     : 256 blocks x 256 thr — all-pairs exact stable rank
//                  (2 sides x 4 cand-chunks x 32 j-chunks); 8 parallel
//                  group-winner tickets bucket by rank/10; final ticket
//                  winner scans + writes 400 outputs.
//
// Bin-width arithmetic: top-2000 cutoff for N(0,1)@262144 is z~2.43; a 13-bit
// bin spans [2.375,2.5) -> ~700 elems; candidates ~2700 < CAP=4096.

#define HW_N   262144
#define NB     8192
#define NBLK1  8
#define CAP    4096
#define K_SEL  2000
#define N_THR  200
#define JCH    32
#define CCH    4
#define NGRP   8      // 2 sides * CCH

__device__ unsigned g_bhist[NBLK1 * NB];
__device__ unsigned g_hdr[4] = {0, 0, 0, 0};   // 0:T_bot 1:T_top 2:cnt_bot 3:cnt_top
__device__ unsigned g_tick = 0;                // D1 ticket (self-resetting)
__device__ unsigned g_gt[NGRP] = {0};          // D3 group tickets (self-resetting)
__device__ unsigned g_ft = 0;                  // D3 final ticket (self-resetting)
__device__ unsigned long long g_top[CAP];      // (~key<<32)|idx : asc = desc value
__device__ unsigned long long g_bot[CAP];      // ( key<<32)|idx : asc = asc value
__device__ unsigned g_prank[2][CAP][JCH];      // partial ranks [side][cand][jchunk]
__device__ float g_pbuck[NGRP][256];

__device__ __forceinline__ unsigned key_of(float x) {
    unsigned u = __float_as_uint(x);
    return (u & 0x80000000u) ? ~u : (u | 0x80000000u);  // ascending key == ascending float
}

// D1: 8 blocks x 1024. Each hists 32768 elems into LDS; ticket winner merges + scans.
__global__ __launch_bounds__(1024) void k_hist_cut(const float* __restrict__ cam) {
    __shared__ unsigned h[NB];
    __shared__ bool s_last;
    const unsigned tid = threadIdx.x, b = blockIdx.x;
    #pragma unroll
    for (int i = 0; i < NB / 1024; i++) h[tid + i * 1024] = 0;
    __syncthreads();
    const float4* cam4 = (const float4*)cam;
    #pragma unroll
    for (int r = 0; r < 8; r++) {
        float4 v = cam4[b * 8192 + r * 1024 + tid];
        atomicAdd(&h[key_of(v.x) >> 19], 1u);
        atomicAdd(&h[key_of(v.y) >> 19], 1u);
        atomicAdd(&h[key_of(v.z) >> 19], 1u);
        atomicAdd(&h[key_of(v.w) >> 19], 1u);
    }
    __syncthreads();
    #pragma unroll
    for (int i = 0; i < NB / 1024; i++)
        g_bhist[b * NB + tid + i * 1024] = h[tid + i * 1024];
    __syncthreads();                     // stores drained (vmcnt(0) before s_barrier)
    if (tid == 0) {
        __threadfence();                 // release per-block hist
        unsigned t = atomicAdd(&g_tick, 1u);
        s_last = (t == NBLK1 - 1);
        if (s_last) g_tick = 0;
    }
    __syncthreads();
    if (!s_last) return;
    __threadfence();                     // acquire all hists

    unsigned c[8] = {0, 0, 0, 0, 0, 0, 0, 0};
    const uint4* bh = (const uint4*)g_bhist;
    #pragma unroll
    for (int hb = 0; hb < NBLK1; hb++) {
        uint4 a = bh[hb * (NB / 4) + 2 * tid];
        uint4 d = bh[hb * (NB / 4) + 2 * tid + 1];
        c[0] += a.x; c[1] += a.y; c[2] += a.z; c[3] += a.w;
        c[4] += d.x; c[5] += d.y; c[6] += d.z; c[7] += d.w;
    }
    unsigned chunk = 0;
    #pragma unroll
    for (int i = 0; i < 8; i++) chunk += c[i];
    h[tid] = chunk;
    __syncthreads();
    for (unsigned off = 1; off < 1024; off <<= 1) {   // Hillis-Steele inclusive
        unsigned v = (tid >= off) ? h[tid - off] : 0u;
        __syncthreads();
        if (tid >= off) h[tid] += v;
        __syncthreads();
    }
    const unsigned r_bot = K_SEL - 1, r_top = HW_N - K_SEL;
    unsigned run = h[tid] - chunk;
    #pragma unroll
    for (int i = 0; i < 8; i++) {
        unsigned nxt = run + c[i];
        if (run <= r_bot && nxt > r_bot) g_hdr[0] = 8 * tid + i;
        if (run <= r_top && nxt > r_top) g_hdr[1] = 8 * tid + i;
        run = nxt;
    }
    if (tid == 0) { g_hdr[2] = 0; g_hdr[3] = 0; }
}

// D2: 256 blocks x 1024. Ballot-aggregated append (2 global atomics/block).
__global__ __launch_bounds__(1024) void k_gather(const float* __restrict__ cam) {
    __shared__ unsigned s_ot[16], s_ob[16], s_bt, s_bb;
    const unsigned tid = threadIdx.x;
    const unsigned i = blockIdx.x * 1024 + tid;
    const unsigned Tb = g_hdr[0], Tt = g_hdr[1];
    const unsigned k = key_of(cam[i]);
    const unsigned bin = k >> 19;
    const bool ft = (bin >= Tt), fb = (bin <= Tb);
    const unsigned long long mt = __ballot(ft), mb = __ballot(fb);
    const unsigned lane = tid & 63, w = tid >> 6;
    if (lane == 0) { s_ot[w] = (unsigned)__popcll(mt); s_ob[w] = (unsigned)__popcll(mb); }
    __syncthreads();
    if (tid == 0) {
        unsigned at = 0, ab = 0;
        #pragma unroll
        for (int j = 0; j < 16; j++) {
            unsigned v = s_ot[j]; s_ot[j] = at; at += v;
            v = s_ob[j]; s_ob[j] = ab; ab += v;
        }
        s_bt = at ? atomicAdd(&g_hdr[3], at) : 0u;
        s_bb = ab ? atomicAdd(&g_hdr[2], ab) : 0u;
    }
    __syncthreads();
    const unsigned long long lmask = (1ull << lane) - 1ull;
    if (ft) {
        unsigned pos = s_bt + s_ot[w] + (unsigned)__popcll(mt & lmask);
        if (pos < CAP) g_top[pos] = ((unsigned long long)(~k) << 32) | i;
    }
    if (fb) {
        unsigned pos = s_bb + s_ob[w] + (unsigned)__popcll(mb & lmask);
        if (pos < CAP) g_bot[pos] = ((unsigned long long)k << 32) | i;
    }
}

// D3: 256 blocks x 256. (side, cc, jc) = (b&1, (b>>1)>>5, (b>>1)&31).
// 4 cands/thread, j-chunk len ~ cnt/32 in LDS (broadcast reads, 4x reuse).
__global__ __launch_bounds__(256) void k_rank(const float* __restrict__ mask,
                                              float* __restrict__ out) {
    __shared__ unsigned long long sj[CAP / JCH + 4];
    __shared__ float bucket[256];
    __shared__ float fbk[512];
    __shared__ bool s_lastg, s_lastf;
    const unsigned tid = threadIdx.x, b = blockIdx.x;
    const unsigned side = b & 1;            // 0: top/forg, 1: bot/backg
    const unsigned q = b >> 1, cc = q >> 5, jc = q & 31;
    unsigned cnt = (side == 0) ? g_hdr[3] : g_hdr[2];
    if (cnt > CAP) cnt = CAP;
    const unsigned long long* rec = (side == 0) ? g_top : g_bot;
    const unsigned lo = (jc * cnt) >> 5, hi = ((jc + 1) * cnt) >> 5;
    const unsigned len = hi - lo;
    for (unsigned e = tid; e < len; e += 256) sj[e] = rec[lo + e];
    __syncthreads();

    const unsigned c0 = cc * 1024 + tid * 4;
    unsigned long long my0 = ~0ull, my1 = ~0ull, my2 = ~0ull, my3 = ~0ull;
    if (c0 + 3 < cnt) {
        my0 = rec[c0]; my1 = rec[c0 + 1]; my2 = rec[c0 + 2]; my3 = rec[c0 + 3];
    } else {
        if (c0 < cnt)     my0 = rec[c0];
        if (c0 + 1 < cnt) my1 = rec[c0 + 1];
        if (c0 + 2 < cnt) my2 = rec[c0 + 2];
        if (c0 + 3 < cnt) my3 = rec[c0 + 3];
    }
    unsigned r0 = 0, r1 = 0, r2 = 0, r3 = 0;
    for (unsigned j = 0; j < len; j++) {    // sj[j] broadcast; reused x4
        const unsigned long long v = sj[j];
        r0 += (v < my0); r1 += (v < my1); r2 += (v < my2); r3 += (v < my3);
    }
    if (c0 < cnt)     g_prank[side][c0][jc]     = r0;
    if (c0 + 1 < cnt) g_prank[side][c0 + 1][jc] = r1;
    if (c0 + 2 < cnt) g_prank[side][c0 + 2][jc] = r2;
    if (c0 + 3 < cnt) g_prank[side][c0 + 3][jc] = r3;
    __syncthreads();                         // stores drained before ticket

    // group ticket: last of the 32 j-blocks for (side,cc) reduces that chunk
    const unsigned grp = side * CCH + cc;
    if (tid == 0) {
        __threadfence();                     // release partial ranks
        unsigned t = atomicAdd(&g_gt[grp], 1u);
        s_lastg = (t == JCH - 1);
        if (s_lastg) g_gt[grp] = 0;
    }
    __syncthreads();
    if (!s_lastg) return;
    __threadfence();                         // acquire group partials

    bucket[tid] = 0.0f;
    __syncthreads();
    #pragma unroll
    for (int i = 0; i < 4; i++) {
        const unsigned c = c0 + i;
        if (c < cnt) {
            const uint4* p = (const uint4*)&g_prank[side][c][0];
            unsigned r = 0;
            #pragma unroll
            for (int u = 0; u < 8; u++) {
                uint4 a = p[u];
                r += a.x + a.y + a.z + a.w;
            }
            if (r < K_SEL) {
                unsigned idx = (unsigned)rec[c];
                float m = mask[idx];
                atomicAdd(&bucket[r / 10], (side == 0) ? m : 1.0f - m);
            }
        }
    }
    __syncthreads();
    g_pbuck[grp][tid] = bucket[tid];
    __syncthreads();                         // stores drained before ticket

    // final ticket: last of 8 group winners sums, scans, writes 400 outputs
    if (tid == 0) {
        __threadfence();                     // release group buckets
        unsigned t = atomicAdd(&g_ft, 1u);
        s_lastf = (t == NGRP - 1);
        if (s_lastf) g_ft = 0;
    }
    __syncthreads();
    if (!s_lastf) return;
    __threadfence();                         // acquire all group buckets

    {
        float f0 = 0.0f, f1 = 0.0f;
        #pragma unroll
        for (int g = 0; g < CCH; g++) {
            f0 += g_pbuck[g][tid];
            f1 += g_pbuck[CCH + g][tid];
        }
        fbk[tid] = f0; fbk[256 + tid] = f1;
    }
    __syncthreads();
    for (unsigned off = 1; off < 256; off <<= 1) {   // scan both sides
        float v0 = (tid >= off) ? fbk[tid - off] : 0.0f;
        float v1 = (tid >= off) ? fbk[256 + tid - off] : 0.0f;
        __syncthreads();
        if (tid >= off) { fbk[tid] += v0; fbk[256 + tid] += v1; }
        __syncthreads();
    }
    if (tid < N_THR) {
        out[tid]         = 100.0f * fbk[tid] / (float)(10 * (tid + 1));
        out[N_THR + tid] = 100.0f * fbk[256 + tid] / (float)(10 * (tid + 1));
    }
}

extern "C" void kernel_launch(void* const* d_in, const int* in_sizes, int n_in,
                              void* d_out, int out_size, void* d_ws, size_t ws_size,
                              hipStream_t stream) {
    const float* cam  = (const float*)d_in[0];
    const float* mask = (const float*)d_in[1];
    float* out = (float*)d_out;

    k_hist_cut<<<NBLK1, 1024, 0, stream>>>(cam);
    k_gather<<<HW_N / 1024, 1024, 0, stream>>>(cam);
    k_rank<<<2 * CCH * JCH, 256, 0, stream>>>(mask, out);
}

// Round 7
// 97.377 us; speedup vs baseline: 3.2925x; 1.0624x over previous
//
#include <hip/hip_runtime.h>

// AccSeeds: exact top-K/bottom-K selection + per-threshold prefix accuracy.
// cam: (512*512) f32, true_mask: (512*512) f32 (0/1).
// out: acc_forg[200] ++ acc_backg[200] (float32), z = 10,20,...,2000.
//
// 3 dispatches (R5 measured cg::grid.sync at ~55 us/sync on MI355X —
// kernel boundaries are cheaper):
//  D1 k_hist_cut : 8 blocks  — per-block LDS hist (13-bit bins); ticket winner
//                  merges 8 hists + scans 8192 bins -> cutoff bins; zeroes buckets.
//  D2 k_gather   : 256 blocks — ballot-aggregated candidate append.
//  D3 k_rank     : 256 blocks x 256 thr — FULL candidate list (<=32 KB) in LDS;
//                  each 32-lane group computes one candidate's complete exact
//                  rank; bucket adds via global float atomics; final ticket
//                  winner scans + writes 400 outputs. (No g_prank round-trip.)
//
// Bin-width arithmetic: top-2000 cutoff for N(0,1)@262144 is z~2.43; a 13-bit
// bin spans [2.375,2.5) -> ~700 elems; candidates ~2700 < CAP=4096.

#define HW_N   262144
#define NB     8192
#define NBLK1  8
#define CAP    4096
#define K_SEL  2000
#define N_THR  200
#define RBLK   256    // D3 blocks (2 sides x 128 chunks)

__device__ unsigned g_bhist[NBLK1 * NB];
__device__ unsigned g_hdr[4] = {0, 0, 0, 0};   // 0:T_bot 1:T_top 2:cnt_bot 3:cnt_top
__device__ unsigned g_tick = 0;                // D1 ticket (self-resetting)
__device__ unsigned g_ft = 0;                  // D3 final ticket (self-resetting)
__device__ unsigned long long g_top[CAP];      // (~key<<32)|idx : asc = desc value
__device__ unsigned long long g_bot[CAP];      // ( key<<32)|idx : asc = asc value
__device__ float g_buck[2][256];               // rank/10 buckets (zeroed by D1 winner)

__device__ __forceinline__ unsigned key_of(float x) {
    unsigned u = __float_as_uint(x);
    return (u & 0x80000000u) ? ~u : (u | 0x80000000u);  // ascending key == ascending float
}

// D1: 8 blocks x 1024. Each hists 32768 elems into LDS; ticket winner merges + scans.
__global__ __launch_bounds__(1024) void k_hist_cut(const float* __restrict__ cam) {
    __shared__ unsigned h[NB];
    __shared__ bool s_last;
    const unsigned tid = threadIdx.x, b = blockIdx.x;
    #pragma unroll
    for (int i = 0; i < NB / 1024; i++) h[tid + i * 1024] = 0;
    __syncthreads();
    const float4* cam4 = (const float4*)cam;
    #pragma unroll
    for (int r = 0; r < 8; r++) {
        float4 v = cam4[b * 8192 + r * 1024 + tid];
        atomicAdd(&h[key_of(v.x) >> 19], 1u);
        atomicAdd(&h[key_of(v.y) >> 19], 1u);
        atomicAdd(&h[key_of(v.z) >> 19], 1u);
        atomicAdd(&h[key_of(v.w) >> 19], 1u);
    }
    __syncthreads();
    #pragma unroll
    for (int i = 0; i < NB / 1024; i++)
        g_bhist[b * NB + tid + i * 1024] = h[tid + i * 1024];
    __syncthreads();                     // stores drained (vmcnt(0) before s_barrier)
    if (tid == 0) {
        __threadfence();                 // release per-block hist
        unsigned t = atomicAdd(&g_tick, 1u);
        s_last = (t == NBLK1 - 1);
        if (s_last) g_tick = 0;
    }
    __syncthreads();
    if (!s_last) return;
    __threadfence();                     // acquire all hists

    unsigned c[8] = {0, 0, 0, 0, 0, 0, 0, 0};
    const uint4* bh = (const uint4*)g_bhist;
    #pragma unroll
    for (int hb = 0; hb < NBLK1; hb++) {
        uint4 a = bh[hb * (NB / 4) + 2 * tid];
        uint4 d = bh[hb * (NB / 4) + 2 * tid + 1];
        c[0] += a.x; c[1] += a.y; c[2] += a.z; c[3] += a.w;
        c[4] += d.x; c[5] += d.y; c[6] += d.z; c[7] += d.w;
    }
    unsigned chunk = 0;
    #pragma unroll
    for (int i = 0; i < 8; i++) chunk += c[i];
    h[tid] = chunk;
    __syncthreads();
    for (unsigned off = 1; off < 1024; off <<= 1) {   // Hillis-Steele inclusive
        unsigned v = (tid >= off) ? h[tid - off] : 0u;
        __syncthreads();
        if (tid >= off) h[tid] += v;
        __syncthreads();
    }
    const unsigned r_bot = K_SEL - 1, r_top = HW_N - K_SEL;
    unsigned run = h[tid] - chunk;
    #pragma unroll
    for (int i = 0; i < 8; i++) {
        unsigned nxt = run + c[i];
        if (run <= r_bot && nxt > r_bot) g_hdr[0] = 8 * tid + i;
        if (run <= r_top && nxt > r_top) g_hdr[1] = 8 * tid + i;
        run = nxt;
    }
    if (tid == 0) { g_hdr[2] = 0; g_hdr[3] = 0; }
    if (tid < 512) ((float*)g_buck)[tid] = 0.0f;   // fresh buckets every launch
}

// D2: 256 blocks x 1024. Ballot-aggregated append (2 global atomics/block).
__global__ __launch_bounds__(1024) void k_gather(const float* __restrict__ cam) {
    __shared__ unsigned s_ot[16], s_ob[16], s_bt, s_bb;
    const unsigned tid = threadIdx.x;
    const unsigned i = blockIdx.x * 1024 + tid;
    const unsigned Tb = g_hdr[0], Tt = g_hdr[1];
    const unsigned k = key_of(cam[i]);
    const unsigned bin = k >> 19;
    const bool ft = (bin >= Tt), fb = (bin <= Tb);
    const unsigned long long mt = __ballot(ft), mb = __ballot(fb);
    const unsigned lane = tid & 63, w = tid >> 6;
    if (lane == 0) { s_ot[w] = (unsigned)__popcll(mt); s_ob[w] = (unsigned)__popcll(mb); }
    __syncthreads();
    if (tid == 0) {
        unsigned at = 0, ab = 0;
        #pragma unroll
        for (int j = 0; j < 16; j++) {
            unsigned v = s_ot[j]; s_ot[j] = at; at += v;
            v = s_ob[j]; s_ob[j] = ab; ab += v;
        }
        s_bt = at ? atomicAdd(&g_hdr[3], at) : 0u;
        s_bb = ab ? atomicAdd(&g_hdr[2], ab) : 0u;
    }
    __syncthreads();
    const unsigned long long lmask = (1ull << lane) - 1ull;
    if (ft) {
        unsigned pos = s_bt + s_ot[w] + (unsigned)__popcll(mt & lmask);
        if (pos < CAP) g_top[pos] = ((unsigned long long)(~k) << 32) | i;
    }
    if (fb) {
        unsigned pos = s_bb + s_ob[w] + (unsigned)__popcll(mb & lmask);
        if (pos < CAP) g_bot[pos] = ((unsigned long long)k << 32) | i;
    }
}

// D3: 256 blocks x 256. side = b&1, chunk cs = b>>1. Full list in LDS;
// 32-lane group per candidate computes its complete exact rank in one pass.
__global__ __launch_bounds__(256) void k_rank(const float* __restrict__ mask,
                                              float* __restrict__ out) {
    __shared__ unsigned long long sj[CAP];        // 32 KB: whole candidate list
    __shared__ float fbk[512];
    __shared__ bool s_lastf;
    const unsigned tid = threadIdx.x, b = blockIdx.x;
    const unsigned side = b & 1;                  // 0: top/forg, 1: bot/backg
    const unsigned cs = b >> 1;                   // 0..127
    unsigned cnt = (side == 0) ? g_hdr[3] : g_hdr[2];
    if (cnt > CAP) cnt = CAP;
    const unsigned long long* rec = (side == 0) ? g_top : g_bot;
    for (unsigned e = tid; e < cnt; e += 256) sj[e] = rec[e];
    __syncthreads();

    const unsigned per = (cnt + 127) >> 7;        // cands per block
    const unsigned c0 = cs * per;
    const unsigned cend = (c0 + per < cnt) ? c0 + per : cnt;
    const unsigned grp = tid >> 5, l32 = tid & 31;
    for (unsigned c = c0 + grp; c < cend; c += 8) {
        const unsigned long long my = sj[c];
        unsigned r = 0;
        for (unsigned j = l32; j < cnt; j += 32)  // lanes read 32 consecutive u64:
            r += (sj[j] < my) ? 1u : 0u;          // 2-way bank alias = free
        r += __shfl_down(r, 16, 32);
        r += __shfl_down(r, 8, 32);
        r += __shfl_down(r, 4, 32);
        r += __shfl_down(r, 2, 32);
        r += __shfl_down(r, 1, 32);
        if (l32 == 0 && r < K_SEL) {
            unsigned idx = (unsigned)my;
            float m = mask[idx];
            atomicAdd(&g_buck[side][r / 10], (side == 0) ? m : 1.0f - m);
        }
    }
    __syncthreads();

    // final ticket: last block scans buckets, writes 400 outputs
    if (tid == 0) {
        __threadfence();                          // release bucket atomics
        unsigned t = atomicAdd(&g_ft, 1u);
        s_lastf = (t == RBLK - 1);
        if (s_lastf) g_ft = 0;
    }
    __syncthreads();
    if (!s_lastf) return;
    __threadfence();                              // acquire all bucket adds

    fbk[tid] = g_buck[0][tid];
    fbk[256 + tid] = g_buck[1][tid];
    __syncthreads();
    for (unsigned off = 1; off < 256; off <<= 1) {   // scan both sides
        float v0 = (tid >= off) ? fbk[tid - off] : 0.0f;
        float v1 = (tid >= off) ? fbk[256 + tid - off] : 0.0f;
        __syncthreads();
        if (tid >= off) { fbk[tid] += v0; fbk[256 + tid] += v1; }
        __syncthreads();
    }
    if (tid < N_THR) {
        out[tid]         = 100.0f * fbk[tid] / (float)(10 * (tid + 1));
        out[N_THR + tid] = 100.0f * fbk[256 + tid] / (float)(10 * (tid + 1));
    }
}

extern "C" void kernel_launch(void* const* d_in, const int* in_sizes, int n_in,
                              void* d_out, int out_size, void* d_ws, size_t ws_size,
                              hipStream_t stream) {
    const float* cam  = (const float*)d_in[0];
    const float* mask = (const float*)d_in[1];
    float* out = (float*)d_out;

    k_hist_cut<<<NBLK1, 1024, 0, stream>>>(cam);
    k_gather<<<HW_N / 1024, 1024, 0, stream>>>(cam);
    k_rank<<<RBLK, 256, 0, stream>>>(mask, out);
}